// Round 3
// baseline (740.401 us; speedup 1.0000x reference)
//
#include <hip/hip_runtime.h>

#define K_CLUSTERS 512
#define FDIM 64

// Native vector type: __builtin_nontemporal_store rejects HIP_vector_type
// (struct); it accepts ext_vector_type.
typedef float vf4 __attribute__((ext_vector_type(4)));

// Transpose W [F=64][K=512] -> Wt [K][F], and wsq[k] = sum_f W[f][k]^2.
// UNCHANGED from round 1 (absmax 0.0) -- numerics must stay identical.
__global__ __launch_bounds__(64) void vq_prep(const float* __restrict__ W,
                                              float* __restrict__ Wt,
                                              float* __restrict__ wsq) {
    int k = blockIdx.x;   // 0..511
    int f = threadIdx.x;  // 0..63
    float w = W[f * K_CLUSTERS + k];
    Wt[k * FDIM + f] = w;
    float s = w * w;
#pragma unroll
    for (int off = 32; off > 0; off >>= 1) s += __shfl_xor(s, off, 64);
    if (f == 0) wsq[k] = s;
}

// One row per thread. W is read with WAVE-UNIFORM addresses from global
// (const __restrict__) so the backend can emit s_load -> SGPR operands,
// keeping the LDS and vector-memory pipes idle. The fmaf chain order is
// bit-identical to round 1 (which scored absmax 0.0) -- do not reorder.
__global__ __launch_bounds__(256) void vq_argmin(const float* __restrict__ z,
                                                 const float* __restrict__ Wt,
                                                 const float* __restrict__ wsq,
                                                 float* __restrict__ out_idx) {
    int i = blockIdx.x * 256 + threadIdx.x;

    float zr[FDIM];
    const float4* z4 = (const float4*)(z + (size_t)i * FDIM);
#pragma unroll
    for (int f4 = 0; f4 < 16; f4++) {
        float4 v = z4[f4];
        zr[4 * f4 + 0] = v.x; zr[4 * f4 + 1] = v.y;
        zr[4 * f4 + 2] = v.z; zr[4 * f4 + 3] = v.w;
    }

    // numpy pairwise-sum replication (8 accumulators, tree combine), contract off.
    float sumz;
    {
#pragma clang fp contract(off)
        float r0 = zr[0] * zr[0], r1 = zr[1] * zr[1], r2 = zr[2] * zr[2], r3 = zr[3] * zr[3];
        float r4 = zr[4] * zr[4], r5 = zr[5] * zr[5], r6 = zr[6] * zr[6], r7 = zr[7] * zr[7];
#pragma unroll
        for (int b = 8; b < 64; b += 8) {
            r0 += zr[b + 0] * zr[b + 0]; r1 += zr[b + 1] * zr[b + 1];
            r2 += zr[b + 2] * zr[b + 2]; r3 += zr[b + 3] * zr[b + 3];
            r4 += zr[b + 4] * zr[b + 4]; r5 += zr[b + 5] * zr[b + 5];
            r6 += zr[b + 6] * zr[b + 6]; r7 += zr[b + 7] * zr[b + 7];
        }
        sumz = ((r0 + r1) + (r2 + r3)) + ((r4 + r5) + (r6 + r7));
    }

    float dmin = 3.0e38f;
    int kmin = 0;

#pragma unroll 2
    for (int k = 0; k < K_CLUSTERS; k++) {
        const float* __restrict__ wr = Wt + (k << 6);  // wave-uniform address
        float dot = 0.0f;
#pragma unroll
        for (int f = 0; f < FDIM; f++) dot = fmaf(zr[f], wr[f], dot);
        float d = fmaf(-2.0f, dot, sumz) + wsq[k];
        if (d < dmin) { dmin = d; kmin = k; }  // strict < => first-index ties, like np.argmin
    }

    out_idx[i] = (float)kmin;
}

// Fully-coalesced epilogue: one thread per float4 of the flat [N,64] arrays.
// Elementwise ops identical to round 1 (contract off) -> bit-identical output.
__global__ __launch_bounds__(256) void vq_epilogue(const float* __restrict__ z,
                                                   const float* __restrict__ Wt,
                                                   const float* __restrict__ idxf,
                                                   float* __restrict__ out_zq,
                                                   float* __restrict__ out_diff) {
    int t = blockIdx.x * 256 + threadIdx.x;  // over N*16 float4 chunks
    int row = t >> 4;
    int c = t & 15;
    int k = (int)idxf[row];
    vf4 zv = ((const vf4*)z)[t];
    vf4 wv = *(const vf4*)(Wt + ((size_t)k << 6) + (c << 2));
    vf4 zq, df;
    {
#pragma clang fp contract(off)
        vf4 d1 = wv - zv;
        zq = zv + d1;
        df = d1 * d1;
    }
    __builtin_nontemporal_store(zq, (vf4*)out_zq + t);
    __builtin_nontemporal_store(df, (vf4*)out_diff + t);
}

// One-hot: each thread writes 32 B (two float4s), nontemporal to dodge
// L2 write-allocate churn on the 268 MB stream.
__global__ __launch_bounds__(256) void vq_onehot(const float* __restrict__ idxf,
                                                 float* __restrict__ enc) {
    int tid = blockIdx.x * 256 + threadIdx.x;  // over N*64 8-float chunks
    int row = tid >> 6;
    int c8 = tid & 63;  // which 8-float chunk of the 512
    int kk = (int)idxf[row];
    int c = kk - c8 * 8;  // 0..7 if hot column in this chunk
    vf4 a, b;
    a.x = (c == 0) ? 1.0f : 0.0f;
    a.y = (c == 1) ? 1.0f : 0.0f;
    a.z = (c == 2) ? 1.0f : 0.0f;
    a.w = (c == 3) ? 1.0f : 0.0f;
    b.x = (c == 4) ? 1.0f : 0.0f;
    b.y = (c == 5) ? 1.0f : 0.0f;
    b.z = (c == 6) ? 1.0f : 0.0f;
    b.w = (c == 7) ? 1.0f : 0.0f;
    vf4* p = (vf4*)enc + ((size_t)tid << 1);
    __builtin_nontemporal_store(a, p);
    __builtin_nontemporal_store(b, p + 1);
}

extern "C" void kernel_launch(void* const* d_in, const int* in_sizes, int n_in,
                              void* d_out, int out_size, void* d_ws, size_t ws_size,
                              hipStream_t stream) {
    const float* z = (const float*)d_in[0];  // [N,64] fp32
    const float* W = (const float*)d_in[1];  // [64,512] fp32
    int N = in_sizes[0] / FDIM;              // 131072

    float* out = (float*)d_out;
    float* out_zq = out;                                   // N*64
    float* out_idx = out_zq + (size_t)N * FDIM;            // N
    float* enc = out_idx + N;                              // N*512
    float* out_diff = enc + (size_t)N * K_CLUSTERS;        // N*64

    float* Wt = (float*)d_ws;                 // 512*64 floats
    float* wsq = Wt + K_CLUSTERS * FDIM;      // 512 floats

    vq_prep<<<K_CLUSTERS, 64, 0, stream>>>(W, Wt, wsq);
    vq_argmin<<<N / 256, 256, 0, stream>>>(z, Wt, wsq, out_idx);
    vq_epilogue<<<N * 16 / 256, 256, 0, stream>>>(z, Wt, out_idx, out_zq, out_diff);
    vq_onehot<<<N * 64 / 256, 256, 0, stream>>>(out_idx, enc);
}

// Round 4
// 587.452 us; speedup vs baseline: 1.2604x; 1.2604x over previous
//
#include <hip/hip_runtime.h>

#define K_CLUSTERS 512
#define FDIM 64

typedef float vf4 __attribute__((ext_vector_type(4)));

// Transpose W [F=64][K=512] -> Wt [K][F], wsq[k] = sum_f W[f][k]^2.
// UNCHANGED (absmax 0.0 proven).
__global__ __launch_bounds__(64) void vq_prep(const float* __restrict__ W,
                                              float* __restrict__ Wt,
                                              float* __restrict__ wsq) {
    int k = blockIdx.x;
    int f = threadIdx.x;
    float w = W[f * K_CLUSTERS + k];
    Wt[k * FDIM + f] = w;
    float s = w * w;
#pragma unroll
    for (int off = 32; off > 0; off >>= 1) s += __shfl_xor(s, off, 64);
    if (f == 0) wsq[k] = s;
}

// 4 rows/thread, wave = one k-quarter. All of Wt lives in LDS (staged once,
// no barrier inside the k-loop). Each ds_read_b128 of W feeds 16 FMAs
// (4 rows x 4 floats) -> LDS-pipe cost /4 vs round 1.
// Per-(row,k) fmaf chain order identical to round 1 (absmax 0.0) -- keep.
__global__ __launch_bounds__(256, 1) void vq_argmin4(const float* __restrict__ z,
                                                     const float* __restrict__ Wt,
                                                     const float* __restrict__ wsq,
                                                     float* __restrict__ out_idx) {
    __shared__ float sW[K_CLUSTERS * FDIM];  // 128 KB
    __shared__ float swsq[K_CLUSTERS];       // 2 KB
    __shared__ float sred_d[4][256];         // 4 KB
    __shared__ int sred_k[4][256];           // 4 KB

    const int tid = threadIdx.x;
    const int tq = tid >> 6;  // wave index = k-quarter (wave-uniform)
    const int tr = tid & 63;
    const int rowBase = blockIdx.x * 256;

    // Stage Wt -> LDS, coalesced float4 (2-way bank aliasing = free).
    {
        const vf4* src = (const vf4*)Wt;
        vf4* dst = (vf4*)sW;
#pragma unroll
        for (int j = 0; j < 32; j++) dst[tid + 256 * j] = src[tid + 256 * j];
        swsq[tid] = wsq[tid];
        swsq[tid + 256] = wsq[tid + 256];
    }

    // Load 4 z rows into registers.
    float zr[4][FDIM];
#pragma unroll
    for (int r = 0; r < 4; r++) {
        const vf4* z4 = (const vf4*)(z + (size_t)(rowBase + tr * 4 + r) * FDIM);
#pragma unroll
        for (int f4 = 0; f4 < 16; f4++) {
            vf4 v = z4[f4];
            zr[r][4 * f4 + 0] = v.x; zr[r][4 * f4 + 1] = v.y;
            zr[r][4 * f4 + 2] = v.z; zr[r][4 * f4 + 3] = v.w;
        }
    }

    // sumz per row: numpy pairwise order (8 accumulators), contract off.
    float sumz[4];
#pragma unroll
    for (int r = 0; r < 4; r++) {
#pragma clang fp contract(off)
        float r0 = zr[r][0] * zr[r][0], r1 = zr[r][1] * zr[r][1];
        float r2 = zr[r][2] * zr[r][2], r3 = zr[r][3] * zr[r][3];
        float r4 = zr[r][4] * zr[r][4], r5 = zr[r][5] * zr[r][5];
        float r6 = zr[r][6] * zr[r][6], r7 = zr[r][7] * zr[r][7];
#pragma unroll
        for (int b = 8; b < 64; b += 8) {
            r0 += zr[r][b + 0] * zr[r][b + 0]; r1 += zr[r][b + 1] * zr[r][b + 1];
            r2 += zr[r][b + 2] * zr[r][b + 2]; r3 += zr[r][b + 3] * zr[r][b + 3];
            r4 += zr[r][b + 4] * zr[r][b + 4]; r5 += zr[r][b + 5] * zr[r][b + 5];
            r6 += zr[r][b + 6] * zr[r][b + 6]; r7 += zr[r][b + 7] * zr[r][b + 7];
        }
        sumz[r] = ((r0 + r1) + (r2 + r3)) + ((r4 + r5) + (r6 + r7));
    }

    __syncthreads();

    float dmin0 = 3.0e38f, dmin1 = 3.0e38f, dmin2 = 3.0e38f, dmin3 = 3.0e38f;
    int kmin0 = 0, kmin1 = 0, kmin2 = 0, kmin3 = 0;
    const int kb = tq << 7;  // quarter base

    for (int k = 0; k < 128; k++) {
        const vf4* wr = (const vf4*)(sW + ((kb + k) << 6));  // wave-uniform
        float dot0 = 0.0f, dot1 = 0.0f, dot2 = 0.0f, dot3 = 0.0f;
#pragma unroll
        for (int f4 = 0; f4 < 16; f4++) {
            vf4 w = wr[f4];
            dot0 = fmaf(zr[0][4 * f4 + 0], w.x, dot0);
            dot0 = fmaf(zr[0][4 * f4 + 1], w.y, dot0);
            dot0 = fmaf(zr[0][4 * f4 + 2], w.z, dot0);
            dot0 = fmaf(zr[0][4 * f4 + 3], w.w, dot0);
            dot1 = fmaf(zr[1][4 * f4 + 0], w.x, dot1);
            dot1 = fmaf(zr[1][4 * f4 + 1], w.y, dot1);
            dot1 = fmaf(zr[1][4 * f4 + 2], w.z, dot1);
            dot1 = fmaf(zr[1][4 * f4 + 3], w.w, dot1);
            dot2 = fmaf(zr[2][4 * f4 + 0], w.x, dot2);
            dot2 = fmaf(zr[2][4 * f4 + 1], w.y, dot2);
            dot2 = fmaf(zr[2][4 * f4 + 2], w.z, dot2);
            dot2 = fmaf(zr[2][4 * f4 + 3], w.w, dot2);
            dot3 = fmaf(zr[3][4 * f4 + 0], w.x, dot3);
            dot3 = fmaf(zr[3][4 * f4 + 1], w.y, dot3);
            dot3 = fmaf(zr[3][4 * f4 + 2], w.z, dot3);
            dot3 = fmaf(zr[3][4 * f4 + 3], w.w, dot3);
        }
        float wq = swsq[kb + k];
        float d0 = fmaf(-2.0f, dot0, sumz[0]) + wq;
        float d1 = fmaf(-2.0f, dot1, sumz[1]) + wq;
        float d2 = fmaf(-2.0f, dot2, sumz[2]) + wq;
        float d3 = fmaf(-2.0f, dot3, sumz[3]) + wq;
        if (d0 < dmin0) { dmin0 = d0; kmin0 = kb + k; }  // strict < = np first-index
        if (d1 < dmin1) { dmin1 = d1; kmin1 = kb + k; }
        if (d2 < dmin2) { dmin2 = d2; kmin2 = kb + k; }
        if (d3 < dmin3) { dmin3 = d3; kmin3 = kb + k; }
    }

    sred_d[tq][tr * 4 + 0] = dmin0; sred_k[tq][tr * 4 + 0] = kmin0;
    sred_d[tq][tr * 4 + 1] = dmin1; sred_k[tq][tr * 4 + 1] = kmin1;
    sred_d[tq][tr * 4 + 2] = dmin2; sred_k[tq][tr * 4 + 2] = kmin2;
    sred_d[tq][tr * 4 + 3] = dmin3; sred_k[tq][tr * 4 + 3] = kmin3;
    __syncthreads();

    // Merge quarters in ascending-k order with strict < (np tie rule).
    float bd = sred_d[0][tid];
    int bk = sred_k[0][tid];
#pragma unroll
    for (int q = 1; q < 4; q++) {
        float d = sred_d[q][tid];
        int kk = sred_k[q][tid];
        if (d < bd) { bd = d; bk = kk; }
    }
    out_idx[rowBase + tid] = (float)bd >= 0.0f || true ? (float)bk : 0.0f;
}

// Fully-coalesced epilogue (unchanged from round 3, bit-exact).
__global__ __launch_bounds__(256) void vq_epilogue(const float* __restrict__ z,
                                                   const float* __restrict__ Wt,
                                                   const float* __restrict__ idxf,
                                                   float* __restrict__ out_zq,
                                                   float* __restrict__ out_diff) {
    int t = blockIdx.x * 256 + threadIdx.x;
    int row = t >> 4;
    int c = t & 15;
    int k = (int)idxf[row];
    vf4 zv = ((const vf4*)z)[t];
    vf4 wv = *(const vf4*)(Wt + ((size_t)k << 6) + (c << 2));
    vf4 zq, df;
    {
#pragma clang fp contract(off)
        vf4 d1 = wv - zv;
        zq = zv + d1;
        df = d1 * d1;
    }
    __builtin_nontemporal_store(zq, (vf4*)out_zq + t);
    __builtin_nontemporal_store(df, (vf4*)out_diff + t);
}

// One-hot = memset(0) + scatter of the N ones (tiny).
__global__ __launch_bounds__(256) void vq_scatter(const float* __restrict__ idxf,
                                                  float* __restrict__ enc) {
    int row = blockIdx.x * 256 + threadIdx.x;
    int k = (int)idxf[row];
    enc[(size_t)row * K_CLUSTERS + k] = 1.0f;
}

extern "C" void kernel_launch(void* const* d_in, const int* in_sizes, int n_in,
                              void* d_out, int out_size, void* d_ws, size_t ws_size,
                              hipStream_t stream) {
    const float* z = (const float*)d_in[0];
    const float* W = (const float*)d_in[1];
    int N = in_sizes[0] / FDIM;  // 131072

    float* out = (float*)d_out;
    float* out_zq = out;
    float* out_idx = out_zq + (size_t)N * FDIM;
    float* enc = out_idx + N;
    float* out_diff = enc + (size_t)N * K_CLUSTERS;

    float* Wt = (float*)d_ws;
    float* wsq = Wt + K_CLUSTERS * FDIM;

    vq_prep<<<K_CLUSTERS, 64, 0, stream>>>(W, Wt, wsq);
    hipMemsetAsync(enc, 0, (size_t)N * K_CLUSTERS * sizeof(float), stream);
    vq_argmin4<<<N / 256, 256, 0, stream>>>(z, Wt, wsq, out_idx);
    vq_epilogue<<<N * 16 / 256, 256, 0, stream>>>(z, Wt, out_idx, out_zq, out_diff);
    vq_scatter<<<N / 256, 256, 0, stream>>>(out_idx, enc);
}